// Round 1
// baseline (207.485 us; speedup 1.0000x reference)
//
#include <hip/hip_runtime.h>
#include <hip/hip_bf16.h>

// HSA prefill (hierarchical sparse attention): per (l, kv-head) workgroup,
// loop over S=16 selected KV blocks of 64 keys. Per-block softmax -> weight
// by w -> accumulate PV. fp32 VALU baseline (correctness-first; MFMA later).
//
// LDS budget: q 16x132f (8.4K) + kv 64x132f (33.8K, shared K then V) +
// p 16x68f (4.3K) = 46.6 KB < 64 KB static limit; grid 512 -> 2 wg/CU.
// Row pad 132 (not 128) so b128 reads spread over all 32 banks.

namespace {

constexpr int kLq  = 256;
constexpr int kHQ  = 32;
constexpr int kH   = 2;
constexpr int kG   = 16;   // query heads per kv head
constexpr int kD   = 128;
constexpr int kS   = 16;   // selected blocks
constexpr int kBS  = 64;   // keys per block
constexpr int kKVRow = kH * kD;  // 256 floats between consecutive kv positions
constexpr float kScaleLog2e = 0.08838834764831845f * 1.4426950408889634f;

constexpr int kPadK = kD + 4;    // 132 float row stride (bank decorrelation)
constexpr int kPadP = kBS + 4;   // 68

__global__ __launch_bounds__(256, 2)
void hsa_prefill_kernel(const float* __restrict__ q,
                        const float* __restrict__ k,
                        const float* __restrict__ v,
                        const float* __restrict__ w,
                        const int*   __restrict__ bidx,
                        float* __restrict__ out)
{
    __shared__ float q_s[kG][kPadK];
    __shared__ float kv_s[kBS][kPadK];   // holds K tile, then V tile
    __shared__ float p_s[kG][kPadP];

    const int bid  = blockIdx.x;   // 0..511
    const int l    = bid >> 1;
    const int h    = bid & 1;
    const int t    = threadIdx.x;
    const int wave = t >> 6;
    const int lane = t & 63;

    // ---- stage Q tile (16 g-rows x 128 d), 512 float4 over 256 threads ----
    {
        int idx = t;
        #pragma unroll
        for (int rep = 0; rep < 2; ++rep, idx += 256) {
            const int g  = idx >> 5;
            const int c4 = (idx & 31) << 2;
            *(float4*)&q_s[g][c4] =
                *(const float4*)(q + (l * kHQ + h * kG + g) * kD + c4);
        }
    }

    // scores-phase mapping: wave owns g-rows [4*wave, 4*wave+4), lane = key u
    const int grow = wave << 2;
    // pv-phase mapping: half-wave owns 2 g-rows across all 128 d
    const int dcol = (lane & 31) << 2;
    const int g0   = ((wave << 1) + (lane >> 5)) << 1;

    float4 o0 = make_float4(0.f, 0.f, 0.f, 0.f);
    float4 o1 = make_float4(0.f, 0.f, 0.f, 0.f);

    const int stage_r  = t >> 5;         // 0..7
    const int stage_c4 = (t & 31) << 2;  // 0..124

    for (int s = 0; s < kS; ++s) {
        const int bi = bidx[(l * kH + h) * kS + s];
        if (bi < 0) continue;            // block-uniform: barrier-safe

        __syncthreads();                 // prior block's LDS reads done
        {   // stage K block: 64 rows x 128 floats (row stride 256 in global)
            const float* kb = k + (size_t)(bi * kBS) * kKVRow + h * kD + stage_c4;
            #pragma unroll
            for (int pass = 0; pass < 8; ++pass) {
                const int row = (pass << 3) + stage_r;
                *(float4*)&kv_s[row][stage_c4] =
                    *(const float4*)(kb + (size_t)row * kKVRow);
            }
        }
        __syncthreads();

        // ---- scores: 4 dot(128) per lane (4 g-rows, one key) ----
        float a0 = 0.f, a1 = 0.f, a2 = 0.f, a3 = 0.f;
        #pragma unroll 8
        for (int d4 = 0; d4 < kD; d4 += 4) {
            const float4 kk = *(const float4*)&kv_s[lane][d4];
            const float4 q0 = *(const float4*)&q_s[grow + 0][d4];
            const float4 q1 = *(const float4*)&q_s[grow + 1][d4];
            const float4 q2 = *(const float4*)&q_s[grow + 2][d4];
            const float4 q3 = *(const float4*)&q_s[grow + 3][d4];
            a0 = fmaf(kk.x, q0.x, a0); a0 = fmaf(kk.y, q0.y, a0);
            a0 = fmaf(kk.z, q0.z, a0); a0 = fmaf(kk.w, q0.w, a0);
            a1 = fmaf(kk.x, q1.x, a1); a1 = fmaf(kk.y, q1.y, a1);
            a1 = fmaf(kk.z, q1.z, a1); a1 = fmaf(kk.w, q1.w, a1);
            a2 = fmaf(kk.x, q2.x, a2); a2 = fmaf(kk.y, q2.y, a2);
            a2 = fmaf(kk.z, q2.z, a2); a2 = fmaf(kk.w, q2.w, a2);
            a3 = fmaf(kk.x, q3.x, a3); a3 = fmaf(kk.y, q3.y, a3);
            a3 = fmaf(kk.z, q3.z, a3); a3 = fmaf(kk.w, q3.w, a3);
        }

        // ---- per-row softmax over 64 keys (intra-wave) + weight ----
        float accs[4] = {a0, a1, a2, a3};
        #pragma unroll
        for (int r = 0; r < 4; ++r) {
            const float a = accs[r];
            float m = a;
            #pragma unroll
            for (int off = 32; off > 0; off >>= 1)
                m = fmaxf(m, __shfl_xor(m, off));
            const float e = exp2f((a - m) * kScaleLog2e);
            float lsum = e;
            #pragma unroll
            for (int off = 32; off > 0; off >>= 1)
                lsum += __shfl_xor(lsum, off);
            const float wc = w[(l * kHQ + h * kG + grow + r) * kS + s];
            p_s[grow + r][lane] = e * (wc / lsum);
        }

        __syncthreads();                 // K reads + P writes complete
        {   // stage V block into the same LDS tile
            const float* vb = v + (size_t)(bi * kBS) * kKVRow + h * kD + stage_c4;
            #pragma unroll
            for (int pass = 0; pass < 8; ++pass) {
                const int row = (pass << 3) + stage_r;
                *(float4*)&kv_s[row][stage_c4] =
                    *(const float4*)(vb + (size_t)row * kKVRow);
            }
        }
        __syncthreads();

        // ---- PV: o[g][d] += p[g][u] * v[u][d] ----
        #pragma unroll 8
        for (int uu = 0; uu < kBS; ++uu) {
            const float4 vv = *(const float4*)&kv_s[uu][dcol];
            const float p0 = p_s[g0 + 0][uu];
            const float p1 = p_s[g0 + 1][uu];
            o0.x = fmaf(p0, vv.x, o0.x); o0.y = fmaf(p0, vv.y, o0.y);
            o0.z = fmaf(p0, vv.z, o0.z); o0.w = fmaf(p0, vv.w, o0.w);
            o1.x = fmaf(p1, vv.x, o1.x); o1.y = fmaf(p1, vv.y, o1.y);
            o1.z = fmaf(p1, vv.z, o1.z); o1.w = fmaf(p1, vv.w, o1.w);
        }
    }

    // out[l][hq=h*16+g][d]
    *(float4*)(out + (l * kHQ + h * kG + g0 + 0) * kD + dcol) = o0;
    *(float4*)(out + (l * kHQ + h * kG + g0 + 1) * kD + dcol) = o1;
}

} // namespace

extern "C" void kernel_launch(void* const* d_in, const int* in_sizes, int n_in,
                              void* d_out, int out_size, void* d_ws, size_t ws_size,
                              hipStream_t stream)
{
    const float* q    = (const float*)d_in[0];
    const float* k    = (const float*)d_in[1];
    const float* v    = (const float*)d_in[2];
    const float* w    = (const float*)d_in[3];
    const int*   bidx = (const int*)d_in[4];
    float* out = (float*)d_out;

    hsa_prefill_kernel<<<dim3(kLq * kH), dim3(256), 0, stream>>>(q, k, v, w, bidx, out);
}

// Round 2
// 145.094 us; speedup vs baseline: 1.4300x; 1.4300x over previous
//
#include <hip/hip_runtime.h>
#include <hip/hip_bf16.h>

// HSA prefill, MFMA bf16 version.
// wg = (l, kv-head), 256 thr = 4 waves. Per selected block s:
//   S^T = K·Q^T via mfma_f32_16x16x32_bf16 (M=u, N=g): wave w owns u-tile w.
//   per-block softmax (no max-sub: scores ~O(5)), weight by w, P -> LDS (B-layout).
//   O^T = V^T·P^T (M=d, N=g): wave w owns d-tiles {2w,2w+1}, accumulate fp32.
// LDS: K_s 64x136 bf16 (17.0K, stride 272B = 17*16 -> b128-aligned, 2-way-free)
//      V_t 128x68 bf16 (17.0K, stride 136B -> b64-aligned reads, 2-way-free writes)
//      P_s 16x72 bf16 (2.3K) + psum 256B = 37.4 KB total.

namespace {

constexpr int kLq = 256, kHQ = 32, kH = 2, kG = 16, kD = 128, kS = 16, kBS = 64;
constexpr int kKVRow = kH * kD;  // 256 floats between consecutive kv positions
constexpr float kScaleLog2e = 0.08838834764831845f * 1.4426950408889634f;

constexpr int kKStr = 136;  // K_s row stride (bf16): 272 B, multiple of 16
constexpr int kVStr = 68;   // V_t row stride (bf16): 136 B, multiple of 8
constexpr int kPStr = 72;   // P_s row stride (bf16): 144 B, multiple of 16

typedef short s16x8 __attribute__((ext_vector_type(8)));
typedef short s16x4 __attribute__((ext_vector_type(4)));
typedef float f32x4 __attribute__((ext_vector_type(4)));

union U32BF2 { unsigned int u; __hip_bfloat162 h; };

static __device__ inline unsigned int pk_bf16(float a, float b) {
    U32BF2 z; z.h = __float22bfloat162_rn(make_float2(a, b));
    return z.u;
}

__global__ __launch_bounds__(256, 2)
void hsa_mfma_kernel(const float* __restrict__ q,
                     const float* __restrict__ k,
                     const float* __restrict__ v,
                     const float* __restrict__ w,
                     const int*   __restrict__ bidx,
                     float* __restrict__ out)
{
    __shared__ unsigned short K_s[kBS][kKStr];
    __shared__ unsigned short V_t[kD][kVStr];
    __shared__ unsigned short P_s[kG][kPStr];
    __shared__ float psum[4][kG];

    const int bid  = blockIdx.x;          // 0..511
    const int l    = bid >> 1;
    const int h    = bid & 1;
    const int t    = threadIdx.x;
    const int wave = t >> 6;
    const int lane = t & 63;
    const int n    = lane & 15;           // N-side index (g) / M-local index
    const int quad = lane >> 4;           // 0..3

    // ---- Q B-fragments (N=g side): lane g=n, k=d = st*32 + quad*8 + j ----
    s16x8 qf[4];
    {
        const float* qb = q + (size_t)(l * kHQ + h * kG + n) * kD + quad * 8;
        #pragma unroll
        for (int st = 0; st < 4; ++st) {
            const float4 f0 = *(const float4*)(qb + st * 32);
            const float4 f1 = *(const float4*)(qb + st * 32 + 4);
            union { s16x8 v; unsigned int u[4]; } z;
            z.u[0] = pk_bf16(f0.x, f0.y); z.u[1] = pk_bf16(f0.z, f0.w);
            z.u[2] = pk_bf16(f1.x, f1.y); z.u[3] = pk_bf16(f1.z, f1.w);
            qf[st] = z.v;
        }
    }

    // ---- per-lane w coefficients for g=n, all 16 s ----
    float wv[kS];
    {
        const float* wb = w + (size_t)(l * kHQ + h * kG + n) * kS;
        #pragma unroll
        for (int i = 0; i < 4; ++i) {
            const float4 f = *(const float4*)(wb + i * 4);
            wv[i*4+0] = f.x; wv[i*4+1] = f.y; wv[i*4+2] = f.z; wv[i*4+3] = f.w;
        }
    }

    f32x4 oacc0 = {0.f, 0.f, 0.f, 0.f};  // O^T d-tile 2*wave
    f32x4 oacc1 = {0.f, 0.f, 0.f, 0.f};  // O^T d-tile 2*wave+1

    const int kr = t >> 5;                // K staging: row 0..7 per pass
    const int kc = (t & 31) << 2;         // K staging: col (float4) 0..124

    for (int s = 0; s < kS; ++s) {
        const int bi = bidx[(l * kH + h) * kS + s];
        if (bi < 0) continue;             // wg-uniform -> barrier-safe

        __syncthreads();                  // previous block's LDS reads done

        // ---- stage K block -> K_s bf16 (rows u, 64x128) ----
        {
            const float* kb = k + (size_t)(bi * kBS) * kKVRow + h * kD + kc;
            #pragma unroll
            for (int pass = 0; pass < 8; ++pass) {
                const int u = pass * 8 + kr;
                const float4 f = *(const float4*)(kb + (size_t)u * kKVRow);
                const unsigned long long pq =
                    ((unsigned long long)pk_bf16(f.z, f.w) << 32) | pk_bf16(f.x, f.y);
                *(unsigned long long*)&K_s[u][kc] = pq;
            }
        }

        // ---- stage V block transposed -> V_t[d][u] bf16 ----
        {
            const float* vb = v + (size_t)(bi * kBS) * kKVRow + h * kD;
            #pragma unroll
            for (int pass = 0; pass < 8; ++pass) {
                const int u0 = (pass * 4 + wave) * 2;
                const float* r0 = vb + (size_t)u0 * kKVRow;
                const float* r1 = r0 + kKVRow;
                #pragma unroll
                for (int i = 0; i < 2; ++i) {
                    const int d = i * 64 + lane;
                    *(unsigned int*)&V_t[d][u0] = pk_bf16(r0[d], r1[d]);
                }
            }
        }
        __syncthreads();

        // ---- scores: S^T[u][g], wave owns u-tile = wave (16 u's) ----
        f32x4 sc = {0.f, 0.f, 0.f, 0.f};
        {
            const int u = wave * 16 + n;  // A-frag m index
            #pragma unroll
            for (int st = 0; st < 4; ++st) {
                const s16x8 af = *(const s16x8*)&K_s[u][st * 32 + quad * 8];
                sc = __builtin_amdgcn_mfma_f32_16x16x32_bf16(af, qf[st], sc, 0, 0, 0);
            }
        }

        // ---- per-block softmax over 64 u for g=n; weight; P -> LDS ----
        {
            const float e0 = exp2f(sc[0] * kScaleLog2e);
            const float e1 = exp2f(sc[1] * kScaleLog2e);
            const float e2 = exp2f(sc[2] * kScaleLog2e);
            const float e3 = exp2f(sc[3] * kScaleLog2e);
            float part = (e0 + e1) + (e2 + e3);     // this wave's 16-u partial (per g)
            part += __shfl_xor(part, 16);
            part += __shfl_xor(part, 32);
            if (quad == 0) psum[wave][n] = part;
            __syncthreads();
            const float tot  = psum[0][n] + psum[1][n] + psum[2][n] + psum[3][n];
            const float coef = wv[s] / tot;
            // lane holds P[g=n][u = wave*16 + quad*4 + r], r=0..3
            const unsigned long long pq =
                ((unsigned long long)pk_bf16(e2 * coef, e3 * coef) << 32) |
                pk_bf16(e0 * coef, e1 * coef);
            *(unsigned long long*)&P_s[n][wave * 16 + quad * 4] = pq;
            __syncthreads();
        }

        // ---- PV: O^T[d][g] += V^T · P^T; wave owns d-tiles {2w, 2w+1} ----
        {
            #pragma unroll
            for (int st = 0; st < 2; ++st) {
                const s16x8 bf = *(const s16x8*)&P_s[n][st * 32 + quad * 8];
                const int ub = st * 32 + quad * 8;
                {
                    const int d = wave * 32 + n;
                    const s16x4 a0 = *(const s16x4*)&V_t[d][ub];
                    const s16x4 a1 = *(const s16x4*)&V_t[d][ub + 4];
                    const s16x8 af = __builtin_shufflevector(a0, a1, 0,1,2,3,4,5,6,7);
                    oacc0 = __builtin_amdgcn_mfma_f32_16x16x32_bf16(af, bf, oacc0, 0, 0, 0);
                }
                {
                    const int d = wave * 32 + 16 + n;
                    const s16x4 a0 = *(const s16x4*)&V_t[d][ub];
                    const s16x4 a1 = *(const s16x4*)&V_t[d][ub + 4];
                    const s16x8 af = __builtin_shufflevector(a0, a1, 0,1,2,3,4,5,6,7);
                    oacc1 = __builtin_amdgcn_mfma_f32_16x16x32_bf16(af, bf, oacc1, 0, 0, 0);
                }
            }
        }
    }

    // ---- epilogue: O^T C-layout -> out[l][h*16+g][d], fp32 ----
    // C/D: col = n = g, row (within 16-tile) = quad*4 + r  -> d consecutive in r
    {
        float* ob = out + (size_t)(l * kHQ + h * kG + n) * kD;
        const int d0 = wave * 32 + quad * 4;
        *(float4*)(ob + d0)      = make_float4(oacc0[0], oacc0[1], oacc0[2], oacc0[3]);
        *(float4*)(ob + d0 + 16) = make_float4(oacc1[0], oacc1[1], oacc1[2], oacc1[3]);
    }
}

} // namespace

extern "C" void kernel_launch(void* const* d_in, const int* in_sizes, int n_in,
                              void* d_out, int out_size, void* d_ws, size_t ws_size,
                              hipStream_t stream)
{
    const float* q    = (const float*)d_in[0];
    const float* k    = (const float*)d_in[1];
    const float* v    = (const float*)d_in[2];
    const float* w    = (const float*)d_in[3];
    const int*   bidx = (const int*)d_in[4];
    float* out = (float*)d_out;

    hsa_mfma_kernel<<<dim3(kLq * kH), dim3(256), 0, stream>>>(q, k, v, w, bidx, out);
}

// Round 3
// 141.240 us; speedup vs baseline: 1.4690x; 1.0273x over previous
//
#include <hip/hip_runtime.h>
#include <hip/hip_bf16.h>

// HSA prefill, MFMA bf16, S-split for occupancy.
// Per-block softmax => the 16 selected blocks are independent:
//   O = sum_s w_s * softmax(K_s Q^T) V_s
// Grid 2048 = (l 256) x (h 2) x (split 4); each wg owns 4 s-blocks; partial O
// combined with fp32 atomicAdd into zeroed d_out.
// Per s-block: wave w computes S^T u-tile w with K A-frags LOADED DIRECTLY
// FROM GLOBAL (16B contiguous, L2-resident -> no K LDS, no K bank conflicts);
// cross-wave softmax denom via psum LDS; P through LDS (B-layout);
// O^T = V^T P^T with V transposed-staged in LDS (conflict-free pattern).
// LDS ~20 KB -> occupancy capped by __launch_bounds__(256,4) = 4 wg/CU.

namespace {

constexpr int kLq = 256, kHQ = 32, kH = 2, kG = 16, kD = 128, kS = 16, kBS = 64;
constexpr int kSplit = 4;               // s-blocks per wg
constexpr int kKVRow = kH * kD;         // 256 floats between consecutive kv rows
constexpr float kScaleLog2e = 0.08838834764831845f * 1.4426950408889634f;

constexpr int kVStr = 68;   // V_t row stride (bf16): 136 B (b64-aligned, 2-way-free)
constexpr int kPStr = 72;   // P_s row stride (bf16): 144 B (b128-aligned)

typedef short s16x8 __attribute__((ext_vector_type(8)));
typedef short s16x4 __attribute__((ext_vector_type(4)));
typedef float f32x4 __attribute__((ext_vector_type(4)));

union U32BF2 { unsigned int u; __hip_bfloat162 h; };

static __device__ inline unsigned int pk_bf16(float a, float b) {
    U32BF2 z; z.h = __float22bfloat162_rn(make_float2(a, b));
    return z.u;
}

static __device__ inline s16x8 pack8(const float4 f0, const float4 f1) {
    union { s16x8 v; unsigned int u[4]; } z;
    z.u[0] = pk_bf16(f0.x, f0.y); z.u[1] = pk_bf16(f0.z, f0.w);
    z.u[2] = pk_bf16(f1.x, f1.y); z.u[3] = pk_bf16(f1.z, f1.w);
    return z.v;
}

__global__ __launch_bounds__(256, 4)
void hsa_mfma_kernel(const float* __restrict__ q,
                     const float* __restrict__ k,
                     const float* __restrict__ v,
                     const float* __restrict__ w,
                     const int*   __restrict__ bidx,
                     float* __restrict__ out)
{
    __shared__ unsigned short V_t[kD][kVStr];
    __shared__ unsigned short P_s[kG][kPStr];
    __shared__ float psum[4][kG];

    const int bid   = blockIdx.x;        // 0..2047
    const int l     = bid >> 3;
    const int h     = (bid >> 2) & 1;
    const int split = bid & 3;
    const int t     = threadIdx.x;
    const int wave  = t >> 6;
    const int lane  = t & 63;
    const int n     = lane & 15;         // N index (g) / M-local index
    const int quad  = lane >> 4;         // 0..3

    // ---- Q B-fragments (N=g side): lane g=n, k=d = st*32 + quad*8 + j ----
    s16x8 qf[4];
    {
        const float* qb = q + (size_t)(l * kHQ + h * kG + n) * kD + quad * 8;
        #pragma unroll
        for (int st = 0; st < 4; ++st)
            qf[st] = pack8(*(const float4*)(qb + st * 32),
                           *(const float4*)(qb + st * 32 + 4));
    }

    // ---- per-lane w coefficients for g=n, this wg's 4 s-slots ----
    const float4 wv = *(const float4*)(w + (size_t)(l * kHQ + h * kG + n) * kS + split * 4);
    const float wvv[4] = {wv.x, wv.y, wv.z, wv.w};

    // ---- this wg's 4 block indices ----
    const int4 bis = *(const int4*)(bidx + (size_t)(l * kH + h) * kS + split * 4);
    const int biv[4] = {bis.x, bis.y, bis.z, bis.w};

    f32x4 oacc0 = {0.f, 0.f, 0.f, 0.f};  // O^T d-tile 2*wave
    f32x4 oacc1 = {0.f, 0.f, 0.f, 0.f};  // O^T d-tile 2*wave+1

    #pragma unroll
    for (int j = 0; j < kSplit; ++j) {
        const int bi = biv[j];
        if (bi < 0) continue;             // wg-uniform -> barrier-safe

        __syncthreads();                  // V_t / P_s safe to overwrite

        // ---- stage V block transposed -> V_t[d][u] bf16 (issued early so
        //      the global loads overlap the score MFMAs below) ----
        {
            const float* vb = v + (size_t)(bi * kBS) * kKVRow + h * kD;
            #pragma unroll
            for (int pass = 0; pass < 8; ++pass) {
                const int u0 = (pass * 4 + wave) * 2;
                const float* r0 = vb + (size_t)u0 * kKVRow;
                const float* r1 = r0 + kKVRow;
                #pragma unroll
                for (int i = 0; i < 2; ++i) {
                    const int d = i * 64 + lane;
                    *(unsigned int*)&V_t[d][u0] = pk_bf16(r0[d], r1[d]);
                }
            }
        }

        // ---- scores: S^T[u][g], wave owns u-tile = wave; K frags from global ----
        f32x4 sc = {0.f, 0.f, 0.f, 0.f};
        {
            const float* kb = k + (size_t)(bi * kBS + wave * 16 + n) * kKVRow
                              + h * kD + quad * 8;
            #pragma unroll
            for (int st = 0; st < 4; ++st) {
                const s16x8 af = pack8(*(const float4*)(kb + st * 32),
                                       *(const float4*)(kb + st * 32 + 4));
                sc = __builtin_amdgcn_mfma_f32_16x16x32_bf16(af, qf[st], sc, 0, 0, 0);
            }
        }

        // ---- per-block softmax over 64 u for g=n ----
        const float e0 = exp2f(sc[0] * kScaleLog2e);
        const float e1 = exp2f(sc[1] * kScaleLog2e);
        const float e2 = exp2f(sc[2] * kScaleLog2e);
        const float e3 = exp2f(sc[3] * kScaleLog2e);
        float part = (e0 + e1) + (e2 + e3);      // wave's 16-u partial (per g)
        part += __shfl_xor(part, 16);
        part += __shfl_xor(part, 32);
        if (quad == 0) psum[wave][n] = part;

        __syncthreads();                  // psum visible AND V_t staged

        {
            const float tot  = psum[0][n] + psum[1][n] + psum[2][n] + psum[3][n];
            const float coef = wvv[j] / tot;
            // lane holds P[g=n][u = wave*16 + quad*4 + r], r=0..3
            const unsigned long long pq =
                ((unsigned long long)pk_bf16(e2 * coef, e3 * coef) << 32) |
                pk_bf16(e0 * coef, e1 * coef);
            *(unsigned long long*)&P_s[n][wave * 16 + quad * 4] = pq;
        }
        __syncthreads();                  // P_s visible

        // ---- PV: O^T[d][g] += V^T · P^T; wave owns d-tiles {2w, 2w+1} ----
        #pragma unroll
        for (int st = 0; st < 2; ++st) {
            const s16x8 bf = *(const s16x8*)&P_s[n][st * 32 + quad * 8];
            const int ub = st * 32 + quad * 8;
            {
                const int d = wave * 32 + n;
                const s16x4 a0 = *(const s16x4*)&V_t[d][ub];
                const s16x4 a1 = *(const s16x4*)&V_t[d][ub + 4];
                const s16x8 af = __builtin_shufflevector(a0, a1, 0,1,2,3,4,5,6,7);
                oacc0 = __builtin_amdgcn_mfma_f32_16x16x32_bf16(af, bf, oacc0, 0, 0, 0);
            }
            {
                const int d = wave * 32 + 16 + n;
                const s16x4 a0 = *(const s16x4*)&V_t[d][ub];
                const s16x4 a1 = *(const s16x4*)&V_t[d][ub + 4];
                const s16x8 af = __builtin_shufflevector(a0, a1, 0,1,2,3,4,5,6,7);
                oacc1 = __builtin_amdgcn_mfma_f32_16x16x32_bf16(af, bf, oacc1, 0, 0, 0);
            }
        }
    }

    // ---- epilogue: atomic-accumulate partial O^T into out[l][h*16+g][d] ----
    {
        float* ob = out + (size_t)(l * kHQ + h * kG + n) * kD;
        const int d0 = wave * 32 + quad * 4;
        #pragma unroll
        for (int i = 0; i < 4; ++i) {
            atomicAdd(ob + d0 + i,      oacc0[i]);
            atomicAdd(ob + d0 + 16 + i, oacc1[i]);
        }
    }
}

} // namespace

extern "C" void kernel_launch(void* const* d_in, const int* in_sizes, int n_in,
                              void* d_out, int out_size, void* d_ws, size_t ws_size,
                              hipStream_t stream)
{
    const float* q    = (const float*)d_in[0];
    const float* k    = (const float*)d_in[1];
    const float* v    = (const float*)d_in[2];
    const float* w    = (const float*)d_in[3];
    const int*   bidx = (const int*)d_in[4];
    float* out = (float*)d_out;

    hipMemsetAsync(out, 0, (size_t)out_size * sizeof(float), stream);
    hsa_mfma_kernel<<<dim3(kLq * kH * kSplit), dim3(256), 0, stream>>>(q, k, v, w, bidx, out);
}